// Round 8
// baseline (7117.233 us; speedup 1.0000x reference)
//
#include <hip/hip_runtime.h>
#include <hip/hip_bf16.h>

#define NN 100000
#define NE 1600000
#define F_IN 512
#define HID 128
#define C_OUT 64
#define L_LAYERS 64
#define SCAN_NB 98  // ceil(NN/1024)

using short8 = __attribute__((ext_vector_type(8))) short;
using f32x4  = __attribute__((ext_vector_type(4))) float;
typedef __attribute__((ext_vector_type(4))) unsigned short ushort4v;

__device__ __forceinline__ short f2bf(float f) {
    __hip_bfloat16 h = __float2bfloat16(f);
    return __builtin_bit_cast(short, h);
}
__device__ __forceinline__ unsigned short f2bfu(float f) {
    __hip_bfloat16 h = __float2bfloat16(f);
    return __builtin_bit_cast(unsigned short, h);
}
__device__ __forceinline__ float bflo(unsigned u) { return __uint_as_float(u << 16); }
__device__ __forceinline__ float bfhi(unsigned u) { return __uint_as_float(u & 0xffff0000u); }
__device__ __forceinline__ float bf2f(unsigned short u) { return __uint_as_float((unsigned)u << 16); }

// ---------------- preprocessing ----------------

__global__ void count_deg(const int* __restrict__ dst, int* __restrict__ cnt) {
    int e = blockIdx.x * blockDim.x + threadIdx.x;
    if (e < NE) atomicAdd(&cnt[dst[e]], 1);
}

__global__ void compute_dinv(const int* __restrict__ cnt, float* __restrict__ dinv) {
    int n = blockIdx.x * blockDim.x + threadIdx.x;
    if (n < NN) dinv[n] = rsqrtf((float)cnt[n] + 1.0f);
}

__global__ __launch_bounds__(256) void scan1(const int* __restrict__ cnt,
                                             int* __restrict__ row_ptr,
                                             int* __restrict__ partial) {
    __shared__ int sdata[256];
    int tid = threadIdx.x;
    int base = blockIdx.x * 1024;
    int v[4];
    int idx0 = base + tid * 4;
#pragma unroll
    for (int i = 0; i < 4; ++i) {
        int idx = idx0 + i;
        v[i] = (idx < NN) ? cnt[idx] : 0;
    }
    int s = v[0] + v[1] + v[2] + v[3];
    sdata[tid] = s;
    __syncthreads();
    int x = s;
    for (int off = 1; off < 256; off <<= 1) {
        int y = (tid >= off) ? sdata[tid - off] : 0;
        __syncthreads();
        x += y;
        sdata[tid] = x;
        __syncthreads();
    }
    int run = x - s;
#pragma unroll
    for (int i = 0; i < 4; ++i) {
        int idx = idx0 + i;
        if (idx < NN) row_ptr[idx] = run;
        run += v[i];
    }
    if (tid == 255) partial[blockIdx.x] = x;
}

__global__ __launch_bounds__(128) void scan2(int* __restrict__ partial) {
    __shared__ int sdata[128];
    int tid = threadIdx.x;
    int v = (tid < SCAN_NB) ? partial[tid] : 0;
    sdata[tid] = v;
    __syncthreads();
    int x = v;
    for (int off = 1; off < 128; off <<= 1) {
        int y = (tid >= off) ? sdata[tid - off] : 0;
        __syncthreads();
        x += y;
        sdata[tid] = x;
        __syncthreads();
    }
    if (tid < SCAN_NB) partial[tid] = x - v;
}

// add block offsets; pad row_ptr[NN..NN+64] = NE for OOB wave preloads
__global__ void scan3(int* __restrict__ row_ptr, const int* __restrict__ partial) {
    int idx = blockIdx.x * blockDim.x + threadIdx.x;
    if (idx < NN) row_ptr[idx] += partial[idx >> 10];
    else if (idx <= NN + 64) row_ptr[idx] = NE;
}

// pack (src, weight-bits) per edge for scalar-load broadcast in the gather
__global__ void scatter_csr(const int* __restrict__ src, const int* __restrict__ dst,
                            const float* __restrict__ dinv, int* __restrict__ fill,
                            int2* __restrict__ edges) {
    int e = blockIdx.x * blockDim.x + threadIdx.x;
    if (e >= NE) return;
    int s = src[e], d = dst[e];
    int pos = atomicAdd(&fill[d], 1);
    edges[pos] = make_int2(s, __float_as_int(dinv[s] * dinv[d]));
}

__global__ __launch_bounds__(256) void prep_wt(const float* __restrict__ Wc,
                                               const float* __restrict__ Win,
                                               __hip_bfloat16* __restrict__ WT,
                                               __hip_bfloat16* __restrict__ WinT) {
    int b = blockIdx.x, tid = threadIdx.x;
    if (b < 64) {
        const float* src = Wc + (size_t)b * HID * HID;
        __hip_bfloat16* dstp = WT + (size_t)b * HID * HID;
        for (int it = 0; it < 64; ++it) {
            int idx = it * 256 + tid;           // n*128 + k
            int n = idx >> 7, k = idx & 127;
            dstp[idx] = __float2bfloat16(src[k * HID + n]);
        }
    } else {
        int j = b - 64;
        for (int it = 0; it < 16; ++it) {
            int gid = j * 4096 + it * 256 + tid;  // n*512 + k
            int n = gid >> 9, k = gid & 511;
            WinT[gid] = __float2bfloat16(Win[k * HID + n]);
        }
    }
}

// ---------------- x0 = relu(X @ W_in + b), bf16 MFMA, 2-tile reg prefetch ----------------
#define LOAD_SET(X0V, X1V, WVV, KT)                                              \
    {                                                                            \
        int k0_ = (KT) * 32;                                                     \
        _Pragma("unroll")                                                        \
        for (int i = 0; i < 2; ++i) {                                            \
            int id = i * 256 + tid;                                              \
            int rr = id >> 2, slot = id & 3;                                     \
            int grow = row0 + rr;                                                \
            X0V[i] = make_float4(0.f, 0.f, 0.f, 0.f); X1V[i] = X0V[i];           \
            if (grow < NN) {                                                     \
                X0V[i] = *(const float4*)&X[(size_t)grow * F_IN + k0_ + slot * 8];     \
                X1V[i] = *(const float4*)&X[(size_t)grow * F_IN + k0_ + slot * 8 + 4]; \
            }                                                                    \
            WVV[i] = *(const uint4*)&WinT[(size_t)rr * F_IN + k0_ + slot * 8];   \
        }                                                                        \
    }

#define PHASE(X0V, X1V, WVV, KT, BUF)                                            \
    {                                                                            \
        short* Xs = SMEM + (BUF) * 4096;                                         \
        short* Wsh = SMEM + 8192 + (BUF) * 4096;                                 \
        _Pragma("unroll")                                                        \
        for (int i = 0; i < 2; ++i) {                                            \
            int id = i * 256 + tid;                                              \
            int rr = id >> 2, slot = id & 3;                                     \
            short8 p;                                                            \
            p[0] = f2bf(X0V[i].x); p[1] = f2bf(X0V[i].y);                        \
            p[2] = f2bf(X0V[i].z); p[3] = f2bf(X0V[i].w);                        \
            p[4] = f2bf(X1V[i].x); p[5] = f2bf(X1V[i].y);                        \
            p[6] = f2bf(X1V[i].z); p[7] = f2bf(X1V[i].w);                        \
            *(short8*)&Xs[rr * 32 + (slot ^ ((rr >> 1) & 3)) * 8] = p;           \
            *(uint4*)&Wsh[rr * 32 + (slot ^ ((rr >> 1) & 3)) * 8] = WVV[i];      \
        }                                                                        \
        __syncthreads();                                                         \
        if ((KT) < 14) LOAD_SET(X0V, X1V, WVV, (KT) + 2);                        \
        short8 a[2], bb[8];                                                      \
        _Pragma("unroll")                                                        \
        for (int m = 0; m < 2; ++m) {                                            \
            int row = w * 32 + m * 16 + r;                                       \
            a[m] = *(short8*)&Xs[row * 32 + (g ^ ((row >> 1) & 3)) * 8];         \
        }                                                                        \
        _Pragma("unroll")                                                        \
        for (int n = 0; n < 8; ++n) {                                            \
            int row = n * 16 + r;                                                \
            bb[n] = *(short8*)&Wsh[row * 32 + (g ^ ((row >> 1) & 3)) * 8];       \
        }                                                                        \
        _Pragma("unroll")                                                        \
        for (int m = 0; m < 2; ++m)                                              \
            _Pragma("unroll")                                                    \
            for (int n = 0; n < 8; ++n)                                          \
                acc[m][n] = __builtin_amdgcn_mfma_f32_16x16x32_bf16(a[m], bb[n], acc[m][n], 0, 0, 0); \
    }

__global__ __launch_bounds__(256) void gemm_x0_mfma(const float* __restrict__ X,
                                                    const __hip_bfloat16* __restrict__ WinT,
                                                    const float* __restrict__ bias,
                                                    __hip_bfloat16* __restrict__ X0b) {
    __shared__ short SMEM[128 * 128];  // 32KB: dbuf tiles, then epilogue staging
    int tid = threadIdx.x;
    int w = tid >> 6, l = tid & 63, g = l >> 4, r = l & 15;
    int row0 = blockIdx.x * 128;
    f32x4 acc[2][8] = {};

    float4 ax0[2], ax1[2]; uint4 aw[2];
    float4 bx0[2], bx1[2]; uint4 bw[2];

    LOAD_SET(ax0, ax1, aw, 0);
    LOAD_SET(bx0, bx1, bw, 1);
    for (int kt = 0; kt < 16; kt += 2) {
        PHASE(ax0, ax1, aw, kt, 0);
        PHASE(bx0, bx1, bw, kt + 1, 1);
    }
    __syncthreads();
    // stage bias+relu result into SMEM (swizzled 16B chunks), then coop vector store
#pragma unroll
    for (int m = 0; m < 2; ++m) {
#pragma unroll
        for (int n = 0; n < 8; ++n) {
            int col = n * 16 + r;
            float bv = bias[col];
#pragma unroll
            for (int q = 0; q < 4; ++q) {
                int row = w * 32 + m * 16 + g * 4 + q;
                float v = fmaxf(acc[m][n][q] + bv, 0.f);
                SMEM[row * 128 + ((col >> 3) ^ (row & 15)) * 8 + (col & 7)] = f2bf(v);
            }
        }
    }
    __syncthreads();
    // 128 rows x 16 chunks of 8 shorts = 2048 uint4 over 256 threads x 8 iters
#pragma unroll
    for (int i = 0; i < 8; ++i) {
        int id = i * 256 + tid;
        int rr = id >> 4, c8 = id & 15;
        int grow = row0 + rr;
        if (grow < NN)
            *(uint4*)&X0b[(size_t)grow * HID + c8 * 8] =
                *(uint4*)&SMEM[rr * 128 + ((c8 ^ (rr & 15)) * 8)];
    }
}

// ---------------- fused layer v4: 32-node tile, half-wave paired gather (8B/lane), W from L2 ----------------
// 256 threads = 4 waves; wave w gathers nodes [w*8, w*8+8) as 4 pairs; lanes 0-31 node A, 32-63 node B
__global__ __launch_bounds__(256, 4) void layer_fused(const uint2* __restrict__ H8,
                                                      const uint2* __restrict__ X08,
                                                      const float* __restrict__ dinv,
                                                      const int* __restrict__ row_ptr,
                                                      const int2* __restrict__ edges,
                                                      const __hip_bfloat16* __restrict__ WTl,
                                                      float beta,
                                                      __hip_bfloat16* __restrict__ Hout,
                                                      float* __restrict__ Zf) {
    __shared__ short Ts[32 * 128];  // 8KB
    int tid = threadIdx.x;
    int w = tid >> 6, l = tid & 63, g = l >> 4, r = l & 15;
    int h = l >> 5;       // half: 0 -> node A, 1 -> node B
    int q = l & 31;       // channels 4q .. 4q+3
    int row0 = blockIdx.x * 32;
    unsigned* TsU = (unsigned*)Ts;

    int nb0 = row0 + w * 8;
    int ep[9];
#pragma unroll
    for (int k = 0; k < 9; ++k) ep[k] = __builtin_amdgcn_readfirstlane(row_ptr[nb0 + k]);

#pragma unroll
    for (int j = 0; j < 4; ++j) {
        int rrA = w * 8 + 2 * j;
        int nA = row0 + rrA;
        int myn = nA + h;           // lane's node
        bool vmy = myn < NN;
        uint2 hs = vmy ? H8[(size_t)(unsigned)myn * 32 + q] : make_uint2(0u, 0u);
        uint2 xv = vmy ? X08[(size_t)(unsigned)myn * 32 + q] : make_uint2(0u, 0u);
        float dv = vmy ? dinv[myn] : 0.f;
        float sw = dv * dv;
        float a0 = sw * bflo(hs.x), a1 = sw * bfhi(hs.x);
        float a2 = sw * bflo(hs.y), a3 = sw * bfhi(hs.y);
        int eA = ep[2 * j], e1A = ep[2 * j + 1];
        int eB = e1A, e1B = ep[2 * j + 2];
        while (eA < e1A || eB < e1B) {
            int cA = e1A - eA; cA = cA > 16 ? 16 : (cA < 0 ? 0 : cA);
            int cB = e1B - eB; cB = cB > 16 ? 16 : (cB < 0 ? 0 : cB);
            uint2 hv[16];
            float ww[16];
#pragma unroll
            for (int u = 0; u < 16; ++u) {
                int2 tA = edges[eA + u];     // wave-uniform -> scalar loads
                int2 tB = edges[eB + u];
                int sA = (u < cA) ? tA.x : 0;
                float wAu = (u < cA) ? __int_as_float(tA.y) : 0.f;
                int sB = (u < cB) ? tB.x : 0;
                float wBu = (u < cB) ? __int_as_float(tB.y) : 0.f;
                int s = h ? sB : sA;
                ww[u] = h ? wBu : wAu;
                hv[u] = H8[(size_t)(unsigned)s * 32 + q];
            }
#pragma unroll
            for (int u = 0; u < 16; ++u) {
                a0 = fmaf(ww[u], bflo(hv[u].x), a0);
                a1 = fmaf(ww[u], bfhi(hv[u].x), a1);
                a2 = fmaf(ww[u], bflo(hv[u].y), a2);
                a3 = fmaf(ww[u], bfhi(hv[u].y), a3);
            }
            eA += cA; eB += cB;
        }
        a0 = 0.9f * a0 + 0.1f * bflo(xv.x);  a1 = 0.9f * a1 + 0.1f * bfhi(xv.x);
        a2 = 0.9f * a2 + 0.1f * bflo(xv.y);  a3 = 0.9f * a3 + 0.1f * bfhi(xv.y);
        unsigned pk0 = (unsigned)f2bfu(a0) | ((unsigned)f2bfu(a1) << 16);
        unsigned pk1 = (unsigned)f2bfu(a2) | ((unsigned)f2bfu(a3) << 16);
        int rr = rrA + h;
        // channels 4q..4q+3 -> slot q>>1, pos (q&1)*4 ; swizzled uint2 write
        *(uint2*)&TsU[rr * 64 + (((q >> 1) ^ (rr & 15)) << 2) + (q & 1) * 2] =
            make_uint2(pk0, pk1);
    }
    __syncthreads();

    // MFMA: wave w -> node-block nb = w&1 (16 nodes), channel-group cg = w>>1 (64 ch)
    // A-fragments (W^T rows) straight from global (L2-hot, 32KB)
    int nb = w & 1, cg = w >> 1;
    f32x4 acc[4] = {};
#pragma unroll
    for (int ks = 0; ks < 4; ++ks) {
        int rrT = nb * 16 + r;
        short8 bT = *(short8*)&Ts[rrT * 128 + ((ks * 4 + g) ^ (rrT & 15)) * 8];
        short8 aW[4];
#pragma unroll
        for (int c = 0; c < 4; ++c) {
            int rowW = (cg * 4 + c) * 16 + r;
            aW[c] = *(const short8*)&WTl[(size_t)rowW * 128 + (ks * 4 + g) * 8];
        }
#pragma unroll
        for (int c = 0; c < 4; ++c)
            acc[c] = __builtin_amdgcn_mfma_f32_16x16x32_bf16(aW[c], bT, acc[c], 0, 0, 0);
    }

    // epilogue: lane holds channels (cg*4+c)*16 + g*4 .. +3 of node nb*16+r
    float omb = 1.0f - beta;
    int node = nb * 16 + r;
    int grow = row0 + node;
    if (grow < NN) {
#pragma unroll
        for (int c = 0; c < 4; ++c) {
            int c0 = (cg * 4 + c) * 16 + g * 4;
            int slotE = c0 >> 3, posE = c0 & 7;
            ushort4v tv = *(ushort4v*)&Ts[node * 128 + (slotE ^ (node & 15)) * 8 + posE];
            float o[4];
#pragma unroll
            for (int p = 0; p < 4; ++p)
                o[p] = fmaxf(omb * bf2f(tv[p]) + beta * acc[c][p], 0.f);
            if (Zf) {
                *(float4*)&Zf[(size_t)grow * HID + c0] = make_float4(o[0], o[1], o[2], o[3]);
            } else {
                ushort4v hv;
#pragma unroll
                for (int p = 0; p < 4; ++p) hv[p] = f2bfu(o[p]);
                *(ushort4v*)&Hout[(size_t)grow * HID + c0] = hv;
            }
        }
    }
}

// ---------------- final: log_softmax(z @ W_out + b_out); z already in d_out ----------------
__global__ __launch_bounds__(64) void final_kernel(const float* __restrict__ Z,
                                                   const float* __restrict__ Wout,
                                                   const float* __restrict__ bout,
                                                   float* __restrict__ lo) {
    int n = blockIdx.x;
    int c = threadIdx.x;
    float logit = bout[c];
    for (int k = 0; k < HID; ++k) {
        logit = fmaf(Z[(size_t)n * HID + k], Wout[k * C_OUT + c], logit);
    }
    float m = logit;
#pragma unroll
    for (int off = 32; off; off >>= 1) m = fmaxf(m, __shfl_xor(m, off));
    float ex = __expf(logit - m);
    float ssum = ex;
#pragma unroll
    for (int off = 32; off; off >>= 1) ssum += __shfl_xor(ssum, off);
    lo[(size_t)n * C_OUT + c] = logit - m - logf(ssum);
}

extern "C" void kernel_launch(void* const* d_in, const int* in_sizes, int n_in,
                              void* d_out, int out_size, void* d_ws, size_t ws_size,
                              hipStream_t stream) {
    const float* x = (const float*)d_in[0];
    const int* ei = (const int*)d_in[1];
    const int* src = ei;
    const int* dst = ei + NE;
    const float* W_in = (const float*)d_in[2];
    const float* b_in = (const float*)d_in[3];
    const float* W_convs = (const float*)d_in[4];
    const float* W_out = (const float*)d_in[5];
    const float* b_out = (const float*)d_in[6];
    float* out = (float*)d_out;

    char* ws = (char*)d_ws;
    float* dinv = (float*)ws;              ws += (size_t)NN * 4;
    int* row_ptr = (int*)ws;               ws += (size_t)(NN + 72) * 4;
    int* fill = (int*)ws;                  ws += (size_t)NN * 4;
    int* partial = (int*)ws;               ws += (size_t)128 * 4;
    int2* edges = (int2*)ws;               ws += (size_t)(NE + 16) * 8;
    __hip_bfloat16* WT = (__hip_bfloat16*)ws;   ws += (size_t)L_LAYERS * HID * HID * 2;
    __hip_bfloat16* WinT = (__hip_bfloat16*)ws; ws += (size_t)F_IN * HID * 2;
    __hip_bfloat16* x0b = (__hip_bfloat16*)ws;  ws += (size_t)NN * HID * 2;
    __hip_bfloat16* HbA = (__hip_bfloat16*)ws;  ws += (size_t)NN * HID * 2;
    __hip_bfloat16* HbB = (__hip_bfloat16*)ws;  ws += (size_t)NN * HID * 2;

    hipMemsetAsync(fill, 0, (size_t)NN * 4, stream);
    count_deg<<<(NE + 255) / 256, 256, 0, stream>>>(dst, fill);
    compute_dinv<<<(NN + 255) / 256, 256, 0, stream>>>(fill, dinv);
    scan1<<<SCAN_NB, 256, 0, stream>>>(fill, row_ptr, partial);
    scan2<<<1, 128, 0, stream>>>(partial);
    scan3<<<(NN + 255) / 256, 256, 0, stream>>>(row_ptr, partial);
    hipMemcpyAsync(fill, row_ptr, (size_t)NN * 4, hipMemcpyDeviceToDevice, stream);
    scatter_csr<<<(NE + 255) / 256, 256, 0, stream>>>(src, dst, dinv, fill, edges);
    prep_wt<<<80, 256, 0, stream>>>(W_convs, W_in, WT, WinT);

    int gemm_blocks = (NN + 127) / 128;
    gemm_x0_mfma<<<gemm_blocks, 256, 0, stream>>>(x, WinT, b_in, x0b);

    int layer_blocks = (NN + 31) / 32;
    float* zf = out;  // last layer writes fp32 z directly into d_out
    for (int l = 0; l < L_LAYERS; ++l) {
        const __hip_bfloat16* h_in = (l == 0) ? x0b : ((l & 1) ? HbA : HbB);
        __hip_bfloat16* h_out = (l & 1) ? HbB : HbA;
        float beta = logf(0.5f / (float)(l + 1) + 1.0f);
        bool last = (l == L_LAYERS - 1);
        layer_fused<<<layer_blocks, 256, 0, stream>>>(
            (const uint2*)h_in, (const uint2*)x0b, dinv, row_ptr, edges,
            WT + (size_t)l * HID * HID, beta,
            h_out, last ? zf : (float*)nullptr);
    }

    final_kernel<<<NN, 64, 0, stream>>>(zf, W_out, b_out, out + (size_t)NN * HID);
}

// Round 9
// 6349.368 us; speedup vs baseline: 1.1209x; 1.1209x over previous
//
#include <hip/hip_runtime.h>
#include <hip/hip_bf16.h>

#define NN 100000
#define NE 1600000
#define F_IN 512
#define HID 128
#define C_OUT 64
#define L_LAYERS 64
#define SCAN_NB 98  // ceil(NN/1024)

using short8 = __attribute__((ext_vector_type(8))) short;
using f32x4  = __attribute__((ext_vector_type(4))) float;
typedef __attribute__((ext_vector_type(4))) unsigned short ushort4v;

__device__ __forceinline__ short f2bf(float f) {
    __hip_bfloat16 h = __float2bfloat16(f);
    return __builtin_bit_cast(short, h);
}
__device__ __forceinline__ unsigned short f2bfu(float f) {
    __hip_bfloat16 h = __float2bfloat16(f);
    return __builtin_bit_cast(unsigned short, h);
}
__device__ __forceinline__ float bflo(unsigned u) { return __uint_as_float(u << 16); }
__device__ __forceinline__ float bfhi(unsigned u) { return __uint_as_float(u & 0xffff0000u); }
__device__ __forceinline__ float bf2f(unsigned short u) { return __uint_as_float((unsigned)u << 16); }

// ---------------- preprocessing ----------------

__global__ void count_deg(const int* __restrict__ dst, int* __restrict__ cnt) {
    int e = blockIdx.x * blockDim.x + threadIdx.x;
    if (e < NE) atomicAdd(&cnt[dst[e]], 1);
}

__global__ void compute_dinv(const int* __restrict__ cnt, float* __restrict__ dinv) {
    int n = blockIdx.x * blockDim.x + threadIdx.x;
    if (n < NN) dinv[n] = rsqrtf((float)cnt[n] + 1.0f);
}

__global__ __launch_bounds__(256) void scan1(const int* __restrict__ cnt,
                                             int* __restrict__ row_ptr,
                                             int* __restrict__ partial) {
    __shared__ int sdata[256];
    int tid = threadIdx.x;
    int base = blockIdx.x * 1024;
    int v[4];
    int idx0 = base + tid * 4;
#pragma unroll
    for (int i = 0; i < 4; ++i) {
        int idx = idx0 + i;
        v[i] = (idx < NN) ? cnt[idx] : 0;
    }
    int s = v[0] + v[1] + v[2] + v[3];
    sdata[tid] = s;
    __syncthreads();
    int x = s;
    for (int off = 1; off < 256; off <<= 1) {
        int y = (tid >= off) ? sdata[tid - off] : 0;
        __syncthreads();
        x += y;
        sdata[tid] = x;
        __syncthreads();
    }
    int run = x - s;
#pragma unroll
    for (int i = 0; i < 4; ++i) {
        int idx = idx0 + i;
        if (idx < NN) row_ptr[idx] = run;
        run += v[i];
    }
    if (tid == 255) partial[blockIdx.x] = x;
}

__global__ __launch_bounds__(128) void scan2(int* __restrict__ partial) {
    __shared__ int sdata[128];
    int tid = threadIdx.x;
    int v = (tid < SCAN_NB) ? partial[tid] : 0;
    sdata[tid] = v;
    __syncthreads();
    int x = v;
    for (int off = 1; off < 128; off <<= 1) {
        int y = (tid >= off) ? sdata[tid - off] : 0;
        __syncthreads();
        x += y;
        sdata[tid] = x;
        __syncthreads();
    }
    if (tid < SCAN_NB) partial[tid] = x - v;
}

// add block offsets; pad row_ptr[NN..NN+64] = NE for OOB wave preloads
__global__ void scan3(int* __restrict__ row_ptr, const int* __restrict__ partial) {
    int idx = blockIdx.x * blockDim.x + threadIdx.x;
    if (idx < NN) row_ptr[idx] += partial[idx >> 10];
    else if (idx <= NN + 64) row_ptr[idx] = NE;
}

// pack (src, weight-bits) per edge for scalar-load broadcast in the gather
__global__ void scatter_csr(const int* __restrict__ src, const int* __restrict__ dst,
                            const float* __restrict__ dinv, int* __restrict__ fill,
                            int2* __restrict__ edges) {
    int e = blockIdx.x * blockDim.x + threadIdx.x;
    if (e >= NE) return;
    int s = src[e], d = dst[e];
    int pos = atomicAdd(&fill[d], 1);
    edges[pos] = make_int2(s, __float_as_int(dinv[s] * dinv[d]));
}

__global__ __launch_bounds__(256) void prep_wt(const float* __restrict__ Wc,
                                               const float* __restrict__ Win,
                                               __hip_bfloat16* __restrict__ WT,
                                               __hip_bfloat16* __restrict__ WinT) {
    int b = blockIdx.x, tid = threadIdx.x;
    if (b < 64) {
        const float* src = Wc + (size_t)b * HID * HID;
        __hip_bfloat16* dstp = WT + (size_t)b * HID * HID;
        for (int it = 0; it < 64; ++it) {
            int idx = it * 256 + tid;           // n*128 + k
            int n = idx >> 7, k = idx & 127;
            dstp[idx] = __float2bfloat16(src[k * HID + n]);
        }
    } else {
        int j = b - 64;
        for (int it = 0; it < 16; ++it) {
            int gid = j * 4096 + it * 256 + tid;  // n*512 + k
            int n = gid >> 9, k = gid & 511;
            WinT[gid] = __float2bfloat16(Win[k * HID + n]);
        }
    }
}

// ---------------- x0 = relu(X @ W_in + b), bf16 MFMA, 2-tile reg prefetch ----------------
#define LOAD_SET(X0V, X1V, WVV, KT)                                              \
    {                                                                            \
        int k0_ = (KT) * 32;                                                     \
        _Pragma("unroll")                                                        \
        for (int i = 0; i < 2; ++i) {                                            \
            int id = i * 256 + tid;                                              \
            int rr = id >> 2, slot = id & 3;                                     \
            int grow = row0 + rr;                                                \
            X0V[i] = make_float4(0.f, 0.f, 0.f, 0.f); X1V[i] = X0V[i];           \
            if (grow < NN) {                                                     \
                X0V[i] = *(const float4*)&X[(size_t)grow * F_IN + k0_ + slot * 8];     \
                X1V[i] = *(const float4*)&X[(size_t)grow * F_IN + k0_ + slot * 8 + 4]; \
            }                                                                    \
            WVV[i] = *(const uint4*)&WinT[(size_t)rr * F_IN + k0_ + slot * 8];   \
        }                                                                        \
    }

#define PHASE(X0V, X1V, WVV, KT, BUF)                                            \
    {                                                                            \
        short* Xs = SMEM + (BUF) * 4096;                                         \
        short* Wsh = SMEM + 8192 + (BUF) * 4096;                                 \
        _Pragma("unroll")                                                        \
        for (int i = 0; i < 2; ++i) {                                            \
            int id = i * 256 + tid;                                              \
            int rr = id >> 2, slot = id & 3;                                     \
            short8 p;                                                            \
            p[0] = f2bf(X0V[i].x); p[1] = f2bf(X0V[i].y);                        \
            p[2] = f2bf(X0V[i].z); p[3] = f2bf(X0V[i].w);                        \
            p[4] = f2bf(X1V[i].x); p[5] = f2bf(X1V[i].y);                        \
            p[6] = f2bf(X1V[i].z); p[7] = f2bf(X1V[i].w);                        \
            *(short8*)&Xs[rr * 32 + (slot ^ ((rr >> 1) & 3)) * 8] = p;           \
            *(uint4*)&Wsh[rr * 32 + (slot ^ ((rr >> 1) & 3)) * 8] = WVV[i];      \
        }                                                                        \
        __syncthreads();                                                         \
        if ((KT) < 14) LOAD_SET(X0V, X1V, WVV, (KT) + 2);                        \
        short8 a[2], bb[8];                                                      \
        _Pragma("unroll")                                                        \
        for (int m = 0; m < 2; ++m) {                                            \
            int row = w * 32 + m * 16 + r;                                       \
            a[m] = *(short8*)&Xs[row * 32 + (g ^ ((row >> 1) & 3)) * 8];         \
        }                                                                        \
        _Pragma("unroll")                                                        \
        for (int n = 0; n < 8; ++n) {                                            \
            int row = n * 16 + r;                                                \
            bb[n] = *(short8*)&Wsh[row * 32 + (g ^ ((row >> 1) & 3)) * 8];       \
        }                                                                        \
        _Pragma("unroll")                                                        \
        for (int m = 0; m < 2; ++m)                                              \
            _Pragma("unroll")                                                    \
            for (int n = 0; n < 8; ++n)                                          \
                acc[m][n] = __builtin_amdgcn_mfma_f32_16x16x32_bf16(a[m], bb[n], acc[m][n], 0, 0, 0); \
    }

__global__ __launch_bounds__(256) void gemm_x0_mfma(const float* __restrict__ X,
                                                    const __hip_bfloat16* __restrict__ WinT,
                                                    const float* __restrict__ bias,
                                                    __hip_bfloat16* __restrict__ X0b) {
    __shared__ short SMEM[128 * 128];  // 32KB: dbuf tiles, then epilogue staging
    int tid = threadIdx.x;
    int w = tid >> 6, l = tid & 63, g = l >> 4, r = l & 15;
    int row0 = blockIdx.x * 128;
    f32x4 acc[2][8] = {};

    float4 ax0[2], ax1[2]; uint4 aw[2];
    float4 bx0[2], bx1[2]; uint4 bw[2];

    LOAD_SET(ax0, ax1, aw, 0);
    LOAD_SET(bx0, bx1, bw, 1);
    for (int kt = 0; kt < 16; kt += 2) {
        PHASE(ax0, ax1, aw, kt, 0);
        PHASE(bx0, bx1, bw, kt + 1, 1);
    }
    __syncthreads();
    // stage bias+relu result into SMEM (swizzled 16B chunks), then coop vector store
#pragma unroll
    for (int m = 0; m < 2; ++m) {
#pragma unroll
        for (int n = 0; n < 8; ++n) {
            int col = n * 16 + r;
            float bv = bias[col];
#pragma unroll
            for (int q = 0; q < 4; ++q) {
                int row = w * 32 + m * 16 + g * 4 + q;
                float v = fmaxf(acc[m][n][q] + bv, 0.f);
                SMEM[row * 128 + ((col >> 3) ^ (row & 15)) * 8 + (col & 7)] = f2bf(v);
            }
        }
    }
    __syncthreads();
    // 128 rows x 16 chunks of 8 shorts = 2048 uint4 over 256 threads x 8 iters
#pragma unroll
    for (int i = 0; i < 8; ++i) {
        int id = i * 256 + tid;
        int rr = id >> 4, c8 = id & 15;
        int grow = row0 + rr;
        if (grow < NN)
            *(uint4*)&X0b[(size_t)grow * HID + c8 * 8] =
                *(uint4*)&SMEM[rr * 128 + ((c8 ^ (rr & 15)) * 8)];
    }
}

// ---------------- fused layer v3b: 64-node tile, paired-node gather, 12-deep batches ----------------
// 512 threads = 8 waves; each wave gathers 8 nodes (4 pairs); LDS: Ts 16KB + Ws 32KB
__global__ __launch_bounds__(512, 6) void layer_fused(const unsigned* __restrict__ H2,
                                                      const unsigned* __restrict__ X02,
                                                      const float* __restrict__ dinv,
                                                      const int* __restrict__ row_ptr,
                                                      const int2* __restrict__ edges,
                                                      const __hip_bfloat16* __restrict__ WTl,
                                                      float beta,
                                                      __hip_bfloat16* __restrict__ Hout,
                                                      float* __restrict__ Zf) {
    __shared__ short Ts[64 * 128];
    __shared__ short Ws[128 * 128];
    int tid = threadIdx.x;
    int w = tid >> 6, l = tid & 63, g = l >> 4, r = l & 15;
    int row0 = blockIdx.x * 64;

    // load W tile (swizzled 16-slot XOR): 2048 uint4 over 512 threads
#pragma unroll
    for (int i = 0; i < 4; ++i) {
        int id = i * 512 + tid;
        int rr = id >> 4, slot = id & 15;
        uint4 wv = *(const uint4*)&WTl[(size_t)id * 8];
        *(uint4*)&Ws[rr * 128 + (slot ^ (rr & 15)) * 8] = wv;
    }

    // gather: wave w -> nodes row0 + w*8 .. +7, processed as 4 concurrent pairs
    unsigned* TsU = (unsigned*)Ts;
    int nb0 = row0 + w * 8;
    int ep[9];
#pragma unroll
    for (int k = 0; k < 9; ++k) ep[k] = __builtin_amdgcn_readfirstlane(row_ptr[nb0 + k]);

#pragma unroll
    for (int j = 0; j < 4; ++j) {
        int rrA = w * 8 + 2 * j, rrB = rrA + 1;
        int nA = row0 + rrA, nB = nA + 1;
        bool vA = nA < NN, vB = nB < NN;
        unsigned hsA = vA ? H2[((unsigned)nA << 6) + l] : 0u;
        unsigned hsB = vB ? H2[((unsigned)nB << 6) + l] : 0u;
        unsigned xvA = vA ? X02[((unsigned)nA << 6) + l] : 0u;
        unsigned xvB = vB ? X02[((unsigned)nB << 6) + l] : 0u;
        float dvA = vA ? dinv[nA] : 0.f, dvB = vB ? dinv[nB] : 0.f;
        float a0A = dvA * dvA * bflo(hsA), a1A = dvA * dvA * bfhi(hsA);
        float a0B = dvB * dvB * bflo(hsB), a1B = dvB * dvB * bfhi(hsB);
        int eA = ep[2 * j], e1A = ep[2 * j + 1];
        int eB = e1A, e1B = ep[2 * j + 2];
        while (eA < e1A || eB < e1B) {
            int cA = e1A - eA; cA = cA > 12 ? 12 : (cA < 0 ? 0 : cA);
            int cB = e1B - eB; cB = cB > 12 ? 12 : (cB < 0 ? 0 : cB);
            int sA[12], sB[12];
            float wA[12], wB[12];
#pragma unroll
            for (int u = 0; u < 12; ++u) {
                int2 t = edges[eA + u];
                sA[u] = (u < cA) ? t.x : 0;
                wA[u] = (u < cA) ? __int_as_float(t.y) : 0.f;
            }
#pragma unroll
            for (int u = 0; u < 12; ++u) {
                int2 t = edges[eB + u];
                sB[u] = (u < cB) ? t.x : 0;
                wB[u] = (u < cB) ? __int_as_float(t.y) : 0.f;
            }
            unsigned hvA[12], hvB[12];
#pragma unroll
            for (int u = 0; u < 12; ++u) hvA[u] = H2[((unsigned)sA[u] << 6) + l];
#pragma unroll
            for (int u = 0; u < 12; ++u) hvB[u] = H2[((unsigned)sB[u] << 6) + l];
#pragma unroll
            for (int u = 0; u < 12; ++u) {
                a0A = fmaf(wA[u], bflo(hvA[u]), a0A);
                a1A = fmaf(wA[u], bfhi(hvA[u]), a1A);
                a0B = fmaf(wB[u], bflo(hvB[u]), a0B);
                a1B = fmaf(wB[u], bfhi(hvB[u]), a1B);
            }
            eA += cA; eB += cB;
        }
        a0A = 0.9f * a0A + 0.1f * bflo(xvA);  a1A = 0.9f * a1A + 0.1f * bfhi(xvA);
        a0B = 0.9f * a0B + 0.1f * bflo(xvB);  a1B = 0.9f * a1B + 0.1f * bfhi(xvB);
        unsigned pkA = (unsigned)f2bfu(a0A) | ((unsigned)f2bfu(a1A) << 16);
        unsigned pkB = (unsigned)f2bfu(a0B) | ((unsigned)f2bfu(a1B) << 16);
        TsU[rrA * 64 + ((l >> 2) ^ (rrA & 15)) * 4 + (l & 3)] = pkA;
        TsU[rrB * 64 + ((l >> 2) ^ (rrB & 15)) * 4 + (l & 3)] = pkB;
    }
    __syncthreads();

    // MFMA phase: wave w -> node-block nb = w&3 (16 nodes), channel-group cg = w>>2 (64 ch)
    int nb = w & 3, cg = w >> 2;
    f32x4 acc[4] = {};
#pragma unroll
    for (int ks = 0; ks < 4; ++ks) {
        int rrT = nb * 16 + r;
        short8 bT = *(short8*)&Ts[rrT * 128 + ((ks * 4 + g) ^ (rrT & 15)) * 8];
        short8 aW[4];
#pragma unroll
        for (int c = 0; c < 4; ++c) {
            int rrW = (cg * 4 + c) * 16 + r;
            aW[c] = *(short8*)&Ws[rrW * 128 + ((ks * 4 + g) ^ (rrW & 15)) * 8];
        }
#pragma unroll
        for (int c = 0; c < 4; ++c)
            acc[c] = __builtin_amdgcn_mfma_f32_16x16x32_bf16(aW[c], bT, acc[c], 0, 0, 0);
    }

    // epilogue: lane holds channels (cg*4+c)*16 + g*4 .. +3 of node nb*16+r
    float omb = 1.0f - beta;
    int node = nb * 16 + r;
    int grow = row0 + node;
    if (grow < NN) {
#pragma unroll
        for (int c = 0; c < 4; ++c) {
            int c0 = (cg * 4 + c) * 16 + g * 4;
            int slotE = c0 >> 3, posE = c0 & 7;
            ushort4v tv = *(ushort4v*)&Ts[node * 128 + (slotE ^ (node & 15)) * 8 + posE];
            float o[4];
#pragma unroll
            for (int q = 0; q < 4; ++q)
                o[q] = fmaxf(omb * bf2f(tv[q]) + beta * acc[c][q], 0.f);
            if (Zf) {
                *(float4*)&Zf[(size_t)grow * HID + c0] = make_float4(o[0], o[1], o[2], o[3]);
            } else {
                ushort4v hv;
#pragma unroll
                for (int q = 0; q < 4; ++q) hv[q] = f2bfu(o[q]);
                *(ushort4v*)&Hout[(size_t)grow * HID + c0] = hv;
            }
        }
    }
}

// ---------------- final v2: LDS-tiled logits + log_softmax, 64 nodes/block ----------------
__global__ __launch_bounds__(256) void final_kernel(const float* __restrict__ Z,
                                                    const float* __restrict__ Wout,
                                                    const float* __restrict__ bout,
                                                    float* __restrict__ lo) {
    __shared__ float Wl[128 * 64];    // [k][c], 32KB
    __shared__ float Zl[64][128];     // 32KB
    int tid = threadIdx.x;
    int w = tid >> 6, c = tid & 63;
    int n0 = blockIdx.x * 64;
    // stage Wout (8192 floats = 2048 float4)
#pragma unroll
    for (int i = 0; i < 8; ++i) {
        int id = i * 256 + tid;
        *(float4*)&Wl[id * 4] = *(const float4*)&Wout[(size_t)id * 4];
    }
    // stage Z rows (64 x 128 floats = 2048 float4)
#pragma unroll
    for (int i = 0; i < 8; ++i) {
        int id = i * 256 + tid;
        int rr = id >> 5, c4 = id & 31;
        int n = n0 + rr;
        float4 v = make_float4(0.f, 0.f, 0.f, 0.f);
        if (n < NN) v = *(const float4*)&Z[(size_t)n * HID + c4 * 4];
        *(float4*)&Zl[rr][c4 * 4] = v;
    }
    __syncthreads();
    float bv = bout[c];
#pragma unroll
    for (int i = 0; i < 4; ++i) {
        int nodeb = i * 16 + w * 4;   // wave w: 4 nodes per pass
        float l0 = 0.f, l1 = 0.f, l2 = 0.f, l3 = 0.f;
#pragma unroll 8
        for (int k = 0; k < 128; ++k) {
            float wv = Wl[k * 64 + c];
            l0 = fmaf(Zl[nodeb + 0][k], wv, l0);
            l1 = fmaf(Zl[nodeb + 1][k], wv, l1);
            l2 = fmaf(Zl[nodeb + 2][k], wv, l2);
            l3 = fmaf(Zl[nodeb + 3][k], wv, l3);
        }
        float lg[4] = {l0 + bv, l1 + bv, l2 + bv, l3 + bv};
#pragma unroll
        for (int j = 0; j < 4; ++j) {
            float logit = lg[j];
            float m = logit;
#pragma unroll
            for (int off = 32; off; off >>= 1) m = fmaxf(m, __shfl_xor(m, off));
            float ex = __expf(logit - m);
            float ssum = ex;
#pragma unroll
            for (int off = 32; off; off >>= 1) ssum += __shfl_xor(ssum, off);
            int n = n0 + nodeb + j;
            if (n < NN) lo[(size_t)n * C_OUT + c] = logit - m - logf(ssum);
        }
    }
}

extern "C" void kernel_launch(void* const* d_in, const int* in_sizes, int n_in,
                              void* d_out, int out_size, void* d_ws, size_t ws_size,
                              hipStream_t stream) {
    const float* x = (const float*)d_in[0];
    const int* ei = (const int*)d_in[1];
    const int* src = ei;
    const int* dst = ei + NE;
    const float* W_in = (const float*)d_in[2];
    const float* b_in = (const float*)d_in[3];
    const float* W_convs = (const float*)d_in[4];
    const float* W_out = (const float*)d_in[5];
    const float* b_out = (const float*)d_in[6];
    float* out = (float*)d_out;

    char* ws = (char*)d_ws;
    float* dinv = (float*)ws;              ws += (size_t)NN * 4;
    int* row_ptr = (int*)ws;               ws += (size_t)(NN + 72) * 4;
    int* fill = (int*)ws;                  ws += (size_t)NN * 4;
    int* partial = (int*)ws;               ws += (size_t)128 * 4;
    int2* edges = (int2*)ws;               ws += (size_t)(NE + 32) * 8;
    __hip_bfloat16* WT = (__hip_bfloat16*)ws;   ws += (size_t)L_LAYERS * HID * HID * 2;
    __hip_bfloat16* WinT = (__hip_bfloat16*)ws; ws += (size_t)F_IN * HID * 2;
    __hip_bfloat16* x0b = (__hip_bfloat16*)ws;  ws += (size_t)NN * HID * 2;
    __hip_bfloat16* HbA = (__hip_bfloat16*)ws;  ws += (size_t)NN * HID * 2;
    __hip_bfloat16* HbB = (__hip_bfloat16*)ws;  ws += (size_t)NN * HID * 2;

    hipMemsetAsync(fill, 0, (size_t)NN * 4, stream);
    count_deg<<<(NE + 255) / 256, 256, 0, stream>>>(dst, fill);
    compute_dinv<<<(NN + 255) / 256, 256, 0, stream>>>(fill, dinv);
    scan1<<<SCAN_NB, 256, 0, stream>>>(fill, row_ptr, partial);
    scan2<<<1, 128, 0, stream>>>(partial);
    scan3<<<(NN + 255) / 256, 256, 0, stream>>>(row_ptr, partial);
    hipMemcpyAsync(fill, row_ptr, (size_t)NN * 4, hipMemcpyDeviceToDevice, stream);
    scatter_csr<<<(NE + 255) / 256, 256, 0, stream>>>(src, dst, dinv, fill, edges);
    prep_wt<<<80, 256, 0, stream>>>(W_convs, W_in, WT, WinT);

    int gemm_blocks = (NN + 127) / 128;
    gemm_x0_mfma<<<gemm_blocks, 256, 0, stream>>>(x, WinT, b_in, x0b);

    int layer_blocks = (NN + 63) / 64;
    float* zf = out;  // last layer writes fp32 z directly into d_out
    for (int l = 0; l < L_LAYERS; ++l) {
        const __hip_bfloat16* h_in = (l == 0) ? x0b : ((l & 1) ? HbA : HbB);
        __hip_bfloat16* h_out = (l & 1) ? HbB : HbA;
        float beta = logf(0.5f / (float)(l + 1) + 1.0f);
        bool last = (l == L_LAYERS - 1);
        layer_fused<<<layer_blocks, 512, 0, stream>>>(
            (const unsigned*)h_in, (const unsigned*)x0b, dinv, row_ptr, edges,
            WT + (size_t)l * HID * HID, beta,
            h_out, last ? zf : (float*)nullptr);
    }

    final_kernel<<<(NN + 63) / 64, 256, 0, stream>>>(zf, W_out, b_out, out + (size_t)NN * HID);
}